// Round 3
// baseline (886.634 us; speedup 1.0000x reference)
//
#include <hip/hip_runtime.h>
#include <hip/hip_bf16.h>
#include <cstdint>

// Problem constants (fixed by the reference)
#define BB 32
#define NN 2048
#define EE 4096
#define HH 4
#define CC 64
#define DD 256            // H*C == D_IN
#define MM (BB*NN)        // 65536 rows

__device__ __forceinline__ float b2f(__hip_bfloat16 x){ return __bfloat162float(x); }
// flag-branched float load: isf=1 -> f32, isf=0 -> bf16
__device__ __forceinline__ float ldany(const void* p, int isf, size_t i){
  return isf ? ((const float*)p)[i] : b2f(((const __hip_bfloat16*)p)[i]);
}

// ---------------- dtype detection ----------------
// If the float payload is packed bf16, the low 16 bits of each u32 word are a
// bf16 of ~N(0,s): its exponent field ((w>>7)&0xFF) is ~always in [100,150].
// If the payload is true f32, those bits are uniform mantissa bits (~20% hit).
__global__ void detect_kernel(const unsigned* __restrict__ w, int* __restrict__ flag){
  __shared__ int cnt;
  if(threadIdx.x == 0) cnt = 0;
  __syncthreads();
  int c = 0;
  #pragma unroll
  for(int i = 0; i < 4; ++i){
    unsigned v = w[threadIdx.x*4 + i];
    unsigned elo = (v >> 7) & 0xFFu;
    if(elo >= 100u && elo <= 150u) ++c;
  }
  atomicAdd(&cnt, c);
  __syncthreads();
  if(threadIdx.x == 0) *flag = (cnt < 128) ? 1 : 0;   // few hits -> true f32
}

// ---------------- param conversion to canonical f32 ----------------
__global__ __launch_bounds__(256) void conv_kernel(const void* __restrict__ src,
    float* __restrict__ dst, int count, const int* __restrict__ flag){
  int isf = *flag;
  int i = blockIdx.x*256 + threadIdx.x;
  if(i < count) dst[i] = ldany(src, isf, i);
}

__global__ __launch_bounds__(256) void conv6_kernel(const void* s0, const void* s1,
    const void* s2, const void* s3, const void* s4, const void* s5,
    float* __restrict__ dst, const int* __restrict__ flag){
  int isf = *flag;
  int i = blockIdx.x*256 + threadIdx.x;       // [0, 1536)
  int seg = i >> 8, off = i & 255;
  const void* s = seg==0?s0 : seg==1?s1 : seg==2?s2 : seg==3?s3 : seg==4?s4 : s5;
  dst[i] = ldany(s, isf, off);
}

// ---------------- GEMM: H[M,256](f32) = A[M,256] @ W[256,256](f32), f32 accum ----------------
__global__ __launch_bounds__(256) void gemm_kernel(const void* __restrict__ A,
    const float* __restrict__ Wf, float* __restrict__ Hout, const int* __restrict__ flag)
{
  __shared__ float As[64][17];
  __shared__ float Bs[16][65];
  const int isf = *flag;
  const int tid  = threadIdx.x;
  const int row0 = blockIdx.x * 64;
  const int col0 = blockIdx.y * 64;
  const int tx = tid & 15, ty = tid >> 4;
  const int ar = tid >> 4, ak = tid & 15;
  const int bk = tid >> 6, bc = tid & 63;
  float acc[4][4] = {};

  for(int k0 = 0; k0 < DD; k0 += 16){
    #pragma unroll
    for(int it = 0; it < 4; ++it){
      int r = ar + it*16;
      As[r][ak] = ldany(A, isf, (size_t)(row0 + r)*DD + k0 + ak);
    }
    #pragma unroll
    for(int it = 0; it < 4; ++it){
      int k = bk + it*4;
      Bs[k][bc] = Wf[(size_t)(k0 + k)*DD + col0 + bc];
    }
    __syncthreads();
    #pragma unroll
    for(int kk = 0; kk < 16; ++kk){
      float a[4], b[4];
      #pragma unroll
      for(int i = 0; i < 4; ++i) a[i] = As[ty*4+i][kk];
      #pragma unroll
      for(int j = 0; j < 4; ++j) b[j] = Bs[kk][tx*4+j];
      #pragma unroll
      for(int i = 0; i < 4; ++i)
        #pragma unroll
        for(int j = 0; j < 4; ++j)
          acc[i][j] += a[i]*b[j];
    }
    __syncthreads();
  }
  #pragma unroll
  for(int i = 0; i < 4; ++i){
    int r = row0 + ty*4 + i;
    #pragma unroll
    for(int j = 0; j < 4; ++j)
      Hout[(size_t)r*DD + col0 + tx*4 + j] = acc[i][j];
  }
}

// ---------------- per-node attention logits ----------------
__global__ __launch_bounds__(256) void att_kernel(const float* __restrict__ H,
    const float* __restrict__ att_src, const float* __restrict__ att_dst,
    float* __restrict__ a_src, float* __restrict__ a_dst)
{
  int idx = blockIdx.x*256 + threadIdx.x;  // (b*N+n)*H + h
  if(idx >= MM*HH) return;
  int h  = idx & (HH-1);
  int bn = idx >> 2;
  const float* hp = H + (size_t)bn*DD + h*CC;
  float ss = 0.f, sd = 0.f;
  #pragma unroll 8
  for(int c = 0; c < CC; ++c){
    float v = hp[c];
    ss += v * att_src[h*CC + c];
    sd += v * att_dst[h*CC + c];
  }
  a_src[idx] = ss; a_dst[idx] = sd;
}

// ---------------- CSR build ----------------
__global__ __launch_bounds__(256) void deg_kernel(const int* __restrict__ dst, int* __restrict__ deg)
{
  int idx = blockIdx.x*256 + threadIdx.x;
  if(idx >= BB*EE) return;
  int b = idx >> 12;                 // EE = 4096
  atomicAdd(&deg[b*NN + dst[idx]], 1);
}

__global__ __launch_bounds__(256) void scan_kernel(const int* __restrict__ deg,
    int* __restrict__ row_ptr, int* __restrict__ cursor)
{
  __shared__ int part[256];
  int b = blockIdx.x, t = threadIdx.x;
  int loc[8], s = 0;
  #pragma unroll
  for(int i = 0; i < 8; ++i){ loc[i] = s; s += deg[b*NN + t*8 + i]; }
  part[t] = s;
  __syncthreads();
  if(t == 0){
    int run = 0;
    for(int i = 0; i < 256; ++i){ int tmp = part[i]; part[i] = run; run += tmp; }
  }
  __syncthreads();
  int base = b*EE + part[t];
  #pragma unroll
  for(int i = 0; i < 8; ++i){
    int v = base + loc[i];
    row_ptr[b*(NN+1) + t*8 + i] = v;
    cursor [b*NN     + t*8 + i] = v;
  }
  if(t == 255) row_ptr[b*(NN+1) + NN] = base + s;
}

__global__ __launch_bounds__(256) void scatter_kernel(const int* __restrict__ src,
    const int* __restrict__ dst, int* __restrict__ cursor, int* __restrict__ srcList)
{
  int idx = blockIdx.x*256 + threadIdx.x;
  if(idx >= BB*EE) return;
  int b = idx >> 12;
  int pos = atomicAdd(&cursor[b*NN + dst[idx]], 1);
  srcList[pos] = src[idx];
}

// ---------------- softmax + aggregate: one wave per (b, dst-node, head) ----------------
// LAYER==1: +bias, ELU, write bf16 x2. LAYER==2: +bias, write output in flag dtype.
template<int LAYER>
__global__ __launch_bounds__(256) void gather_kernel(const float* __restrict__ H,
    const float* __restrict__ a_src, const float* __restrict__ a_dst,
    const int* __restrict__ row_ptr, const int* __restrict__ srcList,
    const float* __restrict__ bias, void* __restrict__ outp,
    const int* __restrict__ flag)
{
  size_t gid = (size_t)blockIdx.x*256 + threadIdx.x;
  int lane = (int)(gid & 63);
  int w    = (int)(gid >> 6);        // (b*NN + d)*HH + h
  if(w >= MM*HH) return;
  int h  = w & (HH-1);
  int bn = w >> 2;                   // b*NN + d
  int b  = bn >> 11;                 // NN = 2048
  int d  = bn & (NN-1);

  int start = row_ptr[b*(NN+1) + d];
  int end   = row_ptr[b*(NN+1) + d + 1];
  float adv  = a_dst[bn*HH + h];
  float self = a_src[bn*HH + h] + adv;
  self = self > 0.f ? self : 0.2f*self;

  float m = self;
  for(int e = start; e < end; ++e){
    int s = srcList[e];
    float v = a_src[(b*NN + s)*HH + h] + adv;
    v = v > 0.f ? v : 0.2f*v;
    m = fmaxf(m, v);
  }
  float den = expf(self - m);
  for(int e = start; e < end; ++e){
    int s = srcList[e];
    float v = a_src[(b*NN + s)*HH + h] + adv;
    v = v > 0.f ? v : 0.2f*v;
    den += expf(v - m);
  }
  float inv = 1.f / (den + 1e-16f);
  float acc = expf(self - m)*inv * H[(size_t)bn*DD + h*CC + lane];
  for(int e = start; e < end; ++e){
    int s = srcList[e];
    float v = a_src[(b*NN + s)*HH + h] + adv;
    v = v > 0.f ? v : 0.2f*v;
    acc += expf(v - m)*inv * H[(size_t)(b*NN + s)*DD + h*CC + lane];
  }
  float o = acc + bias[h*CC + lane];
  size_t oi = (size_t)bn*DD + h*CC + lane;
  if(LAYER == 1){
    o = o > 0.f ? o : expm1f(o);
    ((__hip_bfloat16*)outp)[oi] = __float2bfloat16(o);
  } else {
    if(*flag) ((float*)outp)[oi] = o;
    else      ((__hip_bfloat16*)outp)[oi] = __float2bfloat16(o);
  }
}

extern "C" void kernel_launch(void* const* d_in, const int* in_sizes, int n_in,
                              void* d_out, int out_size, void* d_ws, size_t ws_size,
                              hipStream_t stream)
{
  const void* x_in = d_in[0];
  const int*  srcI = (const int*)d_in[1];
  const int*  dstI = (const int*)d_in[2];
  const void* W1   = d_in[3];
  const void* as1  = d_in[4];
  const void* ad1  = d_in[5];
  const void* b1   = d_in[6];
  const void* W2   = d_in[7];
  const void* as2  = d_in[8];
  const void* ad2  = d_in[9];
  const void* b2   = d_in[10];

  // Workspace layout (~68 MiB total)
  char* ws = (char*)d_ws;
  float* Hf    = (float*)ws; ws += (size_t)MM*DD*sizeof(float);     // 64 MiB
  float* a_src = (float*)ws; ws += (size_t)MM*HH*sizeof(float);     // 1 MiB
  float* a_dst = (float*)ws; ws += (size_t)MM*HH*sizeof(float);     // 1 MiB
  float* W1f   = (float*)ws; ws += (size_t)DD*DD*sizeof(float);     // 256 KiB
  float* W2f   = (float*)ws; ws += (size_t)DD*DD*sizeof(float);     // 256 KiB
  float* attf  = (float*)ws; ws += 1536*sizeof(float);              // as1,ad1,b1,as2,ad2,b2
  int*   deg   = (int*)ws;   ws += (size_t)BB*NN*sizeof(int);
  int*   curs  = (int*)ws;   ws += (size_t)BB*NN*sizeof(int);
  int*   rowp  = (int*)ws;   ws += (size_t)BB*(NN+1)*sizeof(int);
  int*   srcL  = (int*)ws;   ws += (size_t)BB*EE*sizeof(int);
  int*   flag  = (int*)ws;   ws += sizeof(int);
  int*   zero  = (int*)ws;   ws += sizeof(int);

  dim3 ggrid(MM/64, DD/64);                        // 1024 x 4
  const int attBlocks    = (MM*HH)/256;            // 1024
  const int edgeBlocks   = (BB*EE)/256;            // 512
  const int gatherBlocks = (MM*HH*64)/256;         // 65536

  // ---- dtype detection + canonical params ----
  hipMemsetAsync(zero, 0, sizeof(int), stream);
  hipMemsetAsync(deg,  0, (size_t)BB*NN*sizeof(int), stream);
  detect_kernel<<<1, 64, 0, stream>>>((const unsigned*)x_in, flag);
  conv_kernel<<<DD*DD/256, 256, 0, stream>>>(W1, W1f, DD*DD, flag);
  conv_kernel<<<DD*DD/256, 256, 0, stream>>>(W2, W2f, DD*DD, flag);
  conv6_kernel<<<6, 256, 0, stream>>>(as1, ad1, b1, as2, ad2, b2, attf, flag);

  // ---- CSR build (shared by both layers) ----
  deg_kernel    <<<edgeBlocks, 256, 0, stream>>>(dstI, deg);
  scan_kernel   <<<BB,         256, 0, stream>>>(deg, rowp, curs);
  scatter_kernel<<<edgeBlocks, 256, 0, stream>>>(srcI, dstI, curs, srcL);

  // ---- layer 1 ----
  gemm_kernel<<<ggrid, 256, 0, stream>>>(x_in, W1f, Hf, flag);
  att_kernel <<<attBlocks, 256, 0, stream>>>(Hf, attf + 0, attf + 256, a_src, a_dst);
  gather_kernel<1><<<gatherBlocks, 256, 0, stream>>>(Hf, a_src, a_dst, rowp, srcL,
                                                     attf + 512, d_out, flag);
  // ---- layer 2 (x2 staged as bf16 in d_out) ----
  gemm_kernel<<<ggrid, 256, 0, stream>>>(d_out, W2f, Hf, zero);
  att_kernel <<<attBlocks, 256, 0, stream>>>(Hf, attf + 768, attf + 1024, a_src, a_dst);
  gather_kernel<2><<<gatherBlocks, 256, 0, stream>>>(Hf, a_src, a_dst, rowp, srcL,
                                                     attf + 1280, d_out, flag);
}

// Round 4
// 402.001 us; speedup vs baseline: 2.2056x; 2.2056x over previous
//
#include <hip/hip_runtime.h>
#include <hip/hip_bf16.h>
#include <cstdint>

#define BB 32
#define NN 2048
#define EE 4096
#define HH 4
#define CC 64
#define DD 256            // H*C == D_IN
#define MM (BB*NN)        // 65536 rows

typedef __attribute__((ext_vector_type(8))) short bf16x8;
typedef __attribute__((ext_vector_type(4))) float f32x4;

__device__ __forceinline__ float b2f(__hip_bfloat16 x){ return __bfloat162float(x); }
__device__ __forceinline__ float ldany(const void* p, int isf, size_t i){
  return isf ? ((const float*)p)[i] : b2f(((const __hip_bfloat16*)p)[i]);
}
__device__ __forceinline__ void gld_lds16(const void* g, void* l){
  __builtin_amdgcn_global_load_lds((const __attribute__((address_space(1))) uint32_t*)g,
                                   (__attribute__((address_space(3))) uint32_t*)l, 16, 0, 0);
}

// ---------------- dtype detection (unchanged from round 3 — it works) ----------------
__global__ void detect_kernel(const unsigned* __restrict__ w, int* __restrict__ flag){
  __shared__ int cnt;
  if(threadIdx.x == 0) cnt = 0;
  __syncthreads();
  int c = 0;
  #pragma unroll
  for(int i = 0; i < 4; ++i){
    unsigned v = w[threadIdx.x*4 + i];
    unsigned elo = (v >> 7) & 0xFFu;
    if(elo >= 100u && elo <= 150u) ++c;
  }
  atomicAdd(&cnt, c);
  __syncthreads();
  if(threadIdx.x == 0) *flag = (cnt < 128) ? 1 : 0;
}

// ---------------- param prep ----------------
// x -> bf16 (R1)
__global__ __launch_bounds__(256) void convX_kernel(const void* __restrict__ src,
    __hip_bfloat16* __restrict__ dst, const int* __restrict__ flag){
  int isf = *flag;
  size_t i = (size_t)blockIdx.x*256 + threadIdx.x;
  dst[i] = __float2bfloat16(ldany(src, isf, i));
}
// W[k][n] -> WT[n][k] bf16 (write-coalesced)
__global__ __launch_bounds__(256) void convWT_kernel(const void* __restrict__ W,
    __hip_bfloat16* __restrict__ WT, const int* __restrict__ flag){
  int isf = *flag;
  int i = blockIdx.x*256 + threadIdx.x;       // 65536
  WT[i] = __float2bfloat16(ldany(W, isf, (size_t)(i & 255)*256 + (i >> 8)));
}
// att vectors + biases -> f32 canonical
__global__ __launch_bounds__(256) void conv6_kernel(const void* s0, const void* s1,
    const void* s2, const void* s3, const void* s4, const void* s5,
    float* __restrict__ dst, const int* __restrict__ flag){
  int isf = *flag;
  int i = blockIdx.x*256 + threadIdx.x;       // [0, 1536)
  int seg = i >> 8, off = i & 255;
  const void* s = seg==0?s0 : seg==1?s1 : seg==2?s2 : seg==3?s3 : seg==4?s4 : s5;
  dst[i] = ldany(s, isf, off);
}

// ---------------- MFMA GEMM: C[M,256](bf16) = A[M,256](bf16) @ BT[n][k](bf16) ----------------
// 128x128 tile, BK=64, 4 waves (2x2 of 64x64), global_load_lds 16B staging,
// XOR-swizzled LDS (chunk' = chunk ^ (row&7)) -> 2-way-max bank aliasing on ds_read_b128.
__global__ __launch_bounds__(256) void mfma_gemm(const __hip_bfloat16* __restrict__ A,
    const __hip_bfloat16* __restrict__ BT, __hip_bfloat16* __restrict__ C)
{
  __shared__ __align__(16) short lA[128*64];
  __shared__ __align__(16) short lB[128*64];
  const int tid  = threadIdx.x;
  const int w    = tid >> 6, lane = tid & 63;
  const int row0 = blockIdx.x*128, col0 = blockIdx.y*128;
  const int wr   = (w & 1)*64, wc = (w >> 1)*64;
  const int lr   = lane >> 3;              // 0..7: row within staging call
  const int kb_g = (lane & 7) ^ lr;        // swizzled global k-chunk (16B units)
  const int fm   = lane & 15, quad = lane >> 4;
  f32x4 acc[4][4] = {};

  for(int k0 = 0; k0 < 256; k0 += 64){
    #pragma unroll
    for(int c = 0; c < 4; ++c){
      int ra = w*32 + c*8;                 // local row base of this call (8 rows)
      const short* ga = (const short*)A  + (size_t)(row0 + ra + lr)*DD + k0 + kb_g*8;
      const short* gb = (const short*)BT + (size_t)(col0 + ra + lr)*DD + k0 + kb_g*8;
      gld_lds16(ga, &lA[ra*64]);           // lane L -> lA[ra*64 + L*8 .. +8)
      gld_lds16(gb, &lB[ra*64]);
    }
    __syncthreads();
    #pragma unroll
    for(int ks = 0; ks < 2; ++ks){
      bf16x8 af[4], bfr[4];
      int kb = ks*4 + quad;
      #pragma unroll
      for(int i = 0; i < 4; ++i){
        int m = wr + i*16 + fm;
        af[i]  = *(const bf16x8*)&lA[m*64 + ((kb ^ (m & 7))*8)];
        int n = wc + i*16 + fm;
        bfr[i] = *(const bf16x8*)&lB[n*64 + ((kb ^ (n & 7))*8)];
      }
      #pragma unroll
      for(int i = 0; i < 4; ++i)
        #pragma unroll
        for(int j = 0; j < 4; ++j)
          acc[i][j] = __builtin_amdgcn_mfma_f32_16x16x32_bf16(af[i], bfr[j], acc[i][j], 0, 0, 0);
    }
    __syncthreads();
  }
  // C/D layout: col = lane&15, row = quad*4 + reg  [measured: m89/m91]
  #pragma unroll
  for(int i = 0; i < 4; ++i)
    #pragma unroll
    for(int j = 0; j < 4; ++j)
      #pragma unroll
      for(int r = 0; r < 4; ++r){
        int row = row0 + wr + i*16 + quad*4 + r;
        int col = col0 + wc + j*16 + fm;
        C[(size_t)row*DD + col] = __float2bfloat16(acc[i][j][r]);
      }
}

// ---------------- per-node attention logits ----------------
__global__ __launch_bounds__(256) void att_kernel(const __hip_bfloat16* __restrict__ H,
    const float* __restrict__ att_src, const float* __restrict__ att_dst,
    float* __restrict__ a_src, float* __restrict__ a_dst)
{
  int idx = blockIdx.x*256 + threadIdx.x;  // (b*N+n)*H + h
  if(idx >= MM*HH) return;
  int h  = idx & (HH-1);
  int bn = idx >> 2;
  const __hip_bfloat162* hp2 = (const __hip_bfloat162*)(H + (size_t)bn*DD + h*CC);
  const float* as = att_src + h*CC;
  const float* ad = att_dst + h*CC;
  float ss = 0.f, sd = 0.f;
  #pragma unroll
  for(int c = 0; c < 32; ++c){
    __hip_bfloat162 v2 = hp2[c];
    float v0 = b2f(v2.x), v1 = b2f(v2.y);
    ss += v0*as[2*c] + v1*as[2*c+1];
    sd += v0*ad[2*c] + v1*ad[2*c+1];
  }
  a_src[idx] = ss; a_dst[idx] = sd;
}

// ---------------- CSR build ----------------
__global__ __launch_bounds__(256) void deg_kernel(const int* __restrict__ dst, int* __restrict__ degc)
{
  int idx = blockIdx.x*256 + threadIdx.x;
  if(idx >= BB*EE) return;
  int b = idx >> 12;
  atomicAdd(&degc[b*NN + dst[idx]], 1);
}

// reads degc (degree), writes cursor back IN PLACE (each thread touches only its own 8 slots)
__global__ __launch_bounds__(256) void scan_kernel(int* __restrict__ degc, int* __restrict__ row_ptr)
{
  __shared__ int part[256];
  int b = blockIdx.x, t = threadIdx.x;
  int loc[8], s = 0;
  #pragma unroll
  for(int i = 0; i < 8; ++i){ loc[i] = s; s += degc[b*NN + t*8 + i]; }
  part[t] = s;
  __syncthreads();
  if(t == 0){
    int run = 0;
    for(int i = 0; i < 256; ++i){ int tmp = part[i]; part[i] = run; run += tmp; }
  }
  __syncthreads();
  int base = b*EE + part[t];
  #pragma unroll
  for(int i = 0; i < 8; ++i){
    int v = base + loc[i];
    row_ptr[b*(NN+1) + t*8 + i] = v;
    degc   [b*NN     + t*8 + i] = v;
  }
  if(t == 255) row_ptr[b*(NN+1) + NN] = base + s;
}

__global__ __launch_bounds__(256) void scatter_kernel(const int* __restrict__ src,
    const int* __restrict__ dst, int* __restrict__ cursor, unsigned short* __restrict__ srcList)
{
  int idx = blockIdx.x*256 + threadIdx.x;
  if(idx >= BB*EE) return;
  int b = idx >> 12;
  int pos = atomicAdd(&cursor[b*NN + dst[idx]], 1);
  srcList[pos] = (unsigned short)src[idx];
}

// ---------------- single-pass softmax + aggregate: one wave per (b, dst, head) ----------------
// No max subtraction (logits O(1), f32 exp safe; softmax invariant). num/den fused.
template<int LAYER>
__global__ __launch_bounds__(256) void gather_kernel(const __hip_bfloat16* __restrict__ H,
    const float* __restrict__ a_src, const float* __restrict__ a_dst,
    const int* __restrict__ row_ptr, const unsigned short* __restrict__ srcList,
    const float* __restrict__ bias, void* __restrict__ outp,
    const int* __restrict__ flag)
{
  size_t gid = (size_t)blockIdx.x*256 + threadIdx.x;
  int lane = (int)(gid & 63);
  int w    = (int)(gid >> 6);        // (b*NN + d)*HH + h
  if(w >= MM*HH) return;
  int h  = w & (HH-1);
  int bn = w >> 2;
  int b  = bn >> 11;
  int d  = bn & (NN-1);

  int start = row_ptr[b*(NN+1) + d];
  int end   = row_ptr[b*(NN+1) + d + 1];
  float adv  = a_dst[bn*HH + h];
  float self = a_src[bn*HH + h] + adv;
  self = self > 0.f ? self : 0.2f*self;

  float ex  = expf(self);
  float den = ex;
  float acc = ex * b2f(H[(size_t)bn*DD + h*CC + lane]);
  for(int e = start; e < end; ++e){
    int s = srcList[e];
    float v = a_src[(b*NN + s)*HH + h] + adv;
    v = v > 0.f ? v : 0.2f*v;
    float exe = expf(v);
    den += exe;
    acc += exe * b2f(H[(size_t)(b*NN + s)*DD + h*CC + lane]);
  }
  float o = acc / (den + 1e-16f) + bias[h*CC + lane];
  size_t oi = (size_t)bn*DD + h*CC + lane;
  if(LAYER == 1){
    o = o > 0.f ? o : expm1f(o);
    ((__hip_bfloat16*)outp)[oi] = __float2bfloat16(o);
  } else {
    if(*flag) ((float*)outp)[oi] = o;
    else      ((__hip_bfloat16*)outp)[oi] = __float2bfloat16(o);
  }
}

extern "C" void kernel_launch(void* const* d_in, const int* in_sizes, int n_in,
                              void* d_out, int out_size, void* d_ws, size_t ws_size,
                              hipStream_t stream)
{
  const void* x_in = d_in[0];
  const int*  srcI = (const int*)d_in[1];
  const int*  dstI = (const int*)d_in[2];
  const void* W1   = d_in[3];
  const void* as1  = d_in[4];
  const void* ad1  = d_in[5];
  const void* b1   = d_in[6];
  const void* W2   = d_in[7];
  const void* as2  = d_in[8];
  const void* ad2  = d_in[9];
  const void* b2   = d_in[10];

  // Workspace (~67.0 MiB, under the proven 67.75 MiB from round 3)
  char* ws = (char*)d_ws;
  __hip_bfloat16* R1  = (__hip_bfloat16*)ws; ws += (size_t)MM*DD*2;        // 32 MiB: x_bf -> x2
  __hip_bfloat16* R2  = (__hip_bfloat16*)ws; ws += (size_t)MM*DD*2;        // 32 MiB: h1 -> h2
  float* a_src = (float*)ws; ws += (size_t)MM*HH*4;                        // 1 MiB
  float* a_dst = (float*)ws; ws += (size_t)MM*HH*4;                        // 1 MiB
  __hip_bfloat16* W1t = (__hip_bfloat16*)ws; ws += (size_t)DD*DD*2;        // 128 KiB
  __hip_bfloat16* W2t = (__hip_bfloat16*)ws; ws += (size_t)DD*DD*2;        // 128 KiB
  float* attf = (float*)ws; ws += 1536*4;
  int*   degc = (int*)ws;   ws += (size_t)BB*NN*4;                         // degree -> cursor
  int*   rowp = (int*)ws;   ws += (size_t)BB*(NN+1)*4;
  unsigned short* srcL = (unsigned short*)ws; ws += (size_t)BB*EE*2;
  int*   flag = (int*)ws;   ws += 8;

  dim3 ggrid(MM/128, DD/128);                      // 512 x 2
  const int attBlocks    = (MM*HH)/256;            // 1024
  const int edgeBlocks   = (BB*EE)/256;            // 512
  const int gatherBlocks = (MM*HH*64)/256;         // 65536

  // ---- dtype detection + canonical params ----
  hipMemsetAsync(degc, 0, (size_t)BB*NN*4, stream);
  detect_kernel<<<1, 64, 0, stream>>>((const unsigned*)x_in, flag);
  convWT_kernel<<<DD*DD/256, 256, 0, stream>>>(W1, W1t, flag);
  convWT_kernel<<<DD*DD/256, 256, 0, stream>>>(W2, W2t, flag);
  conv6_kernel<<<6, 256, 0, stream>>>(as1, ad1, b1, as2, ad2, b2, attf, flag);
  convX_kernel<<<(int)(((size_t)MM*DD)/256), 256, 0, stream>>>(x_in, R1, flag);

  // ---- CSR build ----
  deg_kernel    <<<edgeBlocks, 256, 0, stream>>>(dstI, degc);
  scan_kernel   <<<BB,         256, 0, stream>>>(degc, rowp);
  scatter_kernel<<<edgeBlocks, 256, 0, stream>>>(srcI, dstI, degc, srcL);

  // ---- layer 1 ----
  mfma_gemm<<<ggrid, 256, 0, stream>>>(R1, W1t, R2);                       // h1 = x @ W1
  att_kernel<<<attBlocks, 256, 0, stream>>>(R2, attf + 0, attf + 256, a_src, a_dst);
  gather_kernel<1><<<gatherBlocks, 256, 0, stream>>>(R2, a_src, a_dst, rowp, srcL,
                                                     attf + 512, R1, flag);  // R1 = x2 (bf16)
  // ---- layer 2 ----
  mfma_gemm<<<ggrid, 256, 0, stream>>>(R1, W2t, R2);                       // h2 = x2 @ W2
  att_kernel<<<attBlocks, 256, 0, stream>>>(R2, attf + 768, attf + 1024, a_src, a_dst);
  gather_kernel<2><<<gatherBlocks, 256, 0, stream>>>(R2, a_src, a_dst, rowp, srcL,
                                                     attf + 1280, d_out, flag);
}

// Round 5
// 308.318 us; speedup vs baseline: 2.8757x; 1.3039x over previous
//
#include <hip/hip_runtime.h>
#include <hip/hip_bf16.h>
#include <cstdint>

#define BB 32
#define NN 2048
#define EE 4096
#define HH 4
#define CC 64
#define DD 256            // H*C == D_IN
#define MM (BB*NN)        // 65536 rows

typedef __attribute__((ext_vector_type(8))) short bf16x8;
typedef __attribute__((ext_vector_type(4))) float f32x4;

__device__ __forceinline__ float b2f(__hip_bfloat16 x){ return __bfloat162float(x); }
__device__ __forceinline__ float u2f(unsigned short u){ return __uint_as_float((unsigned)u << 16); }
__device__ __forceinline__ unsigned short f2u(float f){
  __hip_bfloat16 h = __float2bfloat16(f);
  return *(unsigned short*)&h;
}
__device__ __forceinline__ float ldany(const void* p, int isf, size_t i){
  return isf ? ((const float*)p)[i] : b2f(((const __hip_bfloat16*)p)[i]);
}
__device__ __forceinline__ void gld_lds16(const void* g, void* l){
  __builtin_amdgcn_global_load_lds((const __attribute__((address_space(1))) uint32_t*)g,
                                   (__attribute__((address_space(3))) uint32_t*)l, 16, 0, 0);
}

// ---------------- dtype detection (unchanged — works) ----------------
__global__ void detect_kernel(const unsigned* __restrict__ w, int* __restrict__ flag){
  __shared__ int cnt;
  if(threadIdx.x == 0) cnt = 0;
  __syncthreads();
  int c = 0;
  #pragma unroll
  for(int i = 0; i < 4; ++i){
    unsigned v = w[threadIdx.x*4 + i];
    unsigned elo = (v >> 7) & 0xFFu;
    if(elo >= 100u && elo <= 150u) ++c;
  }
  atomicAdd(&cnt, c);
  __syncthreads();
  if(threadIdx.x == 0) *flag = (cnt < 128) ? 1 : 0;
}

// ---------------- param prep ----------------
// x -> bf16 (vectorized: 4 elements/thread)
__global__ __launch_bounds__(256) void convX_kernel(const void* __restrict__ src,
    unsigned short* __restrict__ dst, const int* __restrict__ flag){
  int isf = *flag;
  size_t i = ((size_t)blockIdx.x*256 + threadIdx.x)*4;
  ushort4 o;
  if(isf){
    float4 v = *(const float4*)((const float*)src + i);
    o.x = f2u(v.x); o.y = f2u(v.y); o.z = f2u(v.z); o.w = f2u(v.w);
  } else {
    o = *(const ushort4*)((const unsigned short*)src + i);
  }
  *(ushort4*)(dst + i) = o;
}
// W[k][n] -> WT[n][k] bf16
__global__ __launch_bounds__(256) void convWT_kernel(const void* __restrict__ W,
    __hip_bfloat16* __restrict__ WT, const int* __restrict__ flag){
  int isf = *flag;
  int i = blockIdx.x*256 + threadIdx.x;       // 65536
  WT[i] = __float2bfloat16(ldany(W, isf, (size_t)(i & 255)*256 + (i >> 8)));
}
// att vectors + biases -> f32 canonical
__global__ __launch_bounds__(256) void conv6_kernel(const void* s0, const void* s1,
    const void* s2, const void* s3, const void* s4, const void* s5,
    float* __restrict__ dst, const int* __restrict__ flag){
  int isf = *flag;
  int i = blockIdx.x*256 + threadIdx.x;       // [0, 1536)
  int seg = i >> 8, off = i & 255;
  const void* s = seg==0?s0 : seg==1?s1 : seg==2?s2 : seg==3?s3 : seg==4?s4 : s5;
  dst[i] = ldany(s, isf, off);
}

// ---------------- MFMA GEMM (unchanged from round 4) ----------------
__global__ __launch_bounds__(256) void mfma_gemm(const __hip_bfloat16* __restrict__ A,
    const __hip_bfloat16* __restrict__ BT, __hip_bfloat16* __restrict__ C)
{
  __shared__ __align__(16) short lA[128*64];
  __shared__ __align__(16) short lB[128*64];
  const int tid  = threadIdx.x;
  const int w    = tid >> 6, lane = tid & 63;
  const int row0 = blockIdx.x*128, col0 = blockIdx.y*128;
  const int wr   = (w & 1)*64, wc = (w >> 1)*64;
  const int lr   = lane >> 3;
  const int kb_g = (lane & 7) ^ lr;
  const int fm   = lane & 15, quad = lane >> 4;
  f32x4 acc[4][4] = {};

  for(int k0 = 0; k0 < 256; k0 += 64){
    #pragma unroll
    for(int c = 0; c < 4; ++c){
      int ra = w*32 + c*8;
      const short* ga = (const short*)A  + (size_t)(row0 + ra + lr)*DD + k0 + kb_g*8;
      const short* gb = (const short*)BT + (size_t)(col0 + ra + lr)*DD + k0 + kb_g*8;
      gld_lds16(ga, &lA[ra*64]);
      gld_lds16(gb, &lB[ra*64]);
    }
    __syncthreads();
    #pragma unroll
    for(int ks = 0; ks < 2; ++ks){
      bf16x8 af[4], bfr[4];
      int kb = ks*4 + quad;
      #pragma unroll
      for(int i = 0; i < 4; ++i){
        int m = wr + i*16 + fm;
        af[i]  = *(const bf16x8*)&lA[m*64 + ((kb ^ (m & 7))*8)];
        int n = wc + i*16 + fm;
        bfr[i] = *(const bf16x8*)&lB[n*64 + ((kb ^ (n & 7))*8)];
      }
      #pragma unroll
      for(int i = 0; i < 4; ++i)
        #pragma unroll
        for(int j = 0; j < 4; ++j)
          acc[i][j] = __builtin_amdgcn_mfma_f32_16x16x32_bf16(af[i], bfr[j], acc[i][j], 0, 0, 0);
    }
    __syncthreads();
  }
  #pragma unroll
  for(int i = 0; i < 4; ++i)
    #pragma unroll
    for(int j = 0; j < 4; ++j)
      #pragma unroll
      for(int r = 0; r < 4; ++r){
        int row = row0 + wr + i*16 + quad*4 + r;
        int col = col0 + wc + j*16 + fm;
        C[(size_t)row*DD + col] = __float2bfloat16(acc[i][j][r]);
      }
}

// ---------------- per-node attention logits ----------------
__global__ __launch_bounds__(256) void att_kernel(const __hip_bfloat16* __restrict__ H,
    const float* __restrict__ att_src, const float* __restrict__ att_dst,
    float* __restrict__ a_src, float* __restrict__ a_dst)
{
  int idx = blockIdx.x*256 + threadIdx.x;  // (b*N+n)*H + h
  if(idx >= MM*HH) return;
  int h  = idx & (HH-1);
  int bn = idx >> 2;
  const __hip_bfloat162* hp2 = (const __hip_bfloat162*)(H + (size_t)bn*DD + h*CC);
  const float* as = att_src + h*CC;
  const float* ad = att_dst + h*CC;
  float ss = 0.f, sd = 0.f;
  #pragma unroll
  for(int c = 0; c < 32; ++c){
    __hip_bfloat162 v2 = hp2[c];
    float v0 = b2f(v2.x), v1 = b2f(v2.y);
    ss += v0*as[2*c] + v1*as[2*c+1];
    sd += v0*ad[2*c] + v1*ad[2*c+1];
  }
  a_src[idx] = ss; a_dst[idx] = sd;
}

// ---------------- CSR build ----------------
__global__ __launch_bounds__(256) void deg_kernel(const int* __restrict__ dst, int* __restrict__ degc)
{
  int idx = blockIdx.x*256 + threadIdx.x;
  if(idx >= BB*EE) return;
  int b = idx >> 12;
  atomicAdd(&degc[b*NN + dst[idx]], 1);
}

__global__ __launch_bounds__(256) void scan_kernel(int* __restrict__ degc, int* __restrict__ row_ptr)
{
  __shared__ int part[256];
  int b = blockIdx.x, t = threadIdx.x;
  int loc[8], s = 0;
  #pragma unroll
  for(int i = 0; i < 8; ++i){ loc[i] = s; s += degc[b*NN + t*8 + i]; }
  part[t] = s;
  __syncthreads();
  if(t == 0){
    int run = 0;
    for(int i = 0; i < 256; ++i){ int tmp = part[i]; part[i] = run; run += tmp; }
  }
  __syncthreads();
  int base = b*EE + part[t];
  #pragma unroll
  for(int i = 0; i < 8; ++i){
    int v = base + loc[i];
    row_ptr[b*(NN+1) + t*8 + i] = v;
    degc   [b*NN     + t*8 + i] = v;
  }
  if(t == 255) row_ptr[b*(NN+1) + NN] = base + s;
}

__global__ __launch_bounds__(256) void scatter_kernel(const int* __restrict__ src,
    const int* __restrict__ dst, int* __restrict__ cursor, unsigned short* __restrict__ srcList)
{
  int idx = blockIdx.x*256 + threadIdx.x;
  if(idx >= BB*EE) return;
  int b = idx >> 12;
  int pos = atomicAdd(&cursor[b*NN + dst[idx]], 1);
  srcList[pos] = (unsigned short)src[idx];
}

// ---------------- normalized softmax weights: one THREAD per (b, dst, head) ----------------
__global__ __launch_bounds__(256) void alpha_kernel(const float* __restrict__ a_src,
    const float* __restrict__ a_dst, const int* __restrict__ row_ptr,
    const unsigned short* __restrict__ srcList, float* __restrict__ alpha,
    float* __restrict__ alphaSelf)
{
  int idx = blockIdx.x*256 + threadIdx.x;   // (b*NN + d)*HH + h
  if(idx >= MM*HH) return;
  int h  = idx & (HH-1);
  int bn = idx >> 2;
  int b  = bn >> 11;
  int d  = bn & (NN-1);
  int start = row_ptr[b*(NN+1) + d];
  int end   = row_ptr[b*(NN+1) + d + 1];
  float adv  = a_dst[idx];
  float self = a_src[idx] + adv;
  self = self > 0.f ? self : 0.2f*self;
  float exs = __expf(self), den = exs;
  for(int e = start; e < end; ++e){
    int s = srcList[e];
    float v = a_src[(b*NN + s)*HH + h] + adv;
    v = v > 0.f ? v : 0.2f*v;
    float ex = __expf(v);
    alpha[e*HH + h] = ex;
    den += ex;
  }
  float inv = 1.f / (den + 1e-16f);
  alphaSelf[idx] = exs * inv;
  for(int e = start; e < end; ++e) alpha[e*HH + h] *= inv;
}

// ---------------- aggregate: one wave per (b, dst); lane owns 4 channels ----------------
template<int LAYER>
__global__ __launch_bounds__(256) void gather_kernel(const __hip_bfloat16* __restrict__ H,
    const float* __restrict__ alpha, const float* __restrict__ alphaSelf,
    const int* __restrict__ row_ptr, const unsigned short* __restrict__ srcList,
    const float* __restrict__ bias, void* __restrict__ outp,
    const int* __restrict__ flag)
{
  int wid  = (int)(((size_t)blockIdx.x*256 + threadIdx.x) >> 6);  // b*NN + d
  int lane = threadIdx.x & 63;
  if(wid >= MM) return;
  int b = wid >> 11, d = wid & (NN-1);
  int head = lane >> 4;                    // channel group lane*4.. -> head = lane>>4
  int start = row_ptr[b*(NN+1) + d];
  int end   = row_ptr[b*(NN+1) + d + 1];
  const unsigned short* Hu = (const unsigned short*)H;

  float aS = alphaSelf[wid*HH + head];
  ushort4 hv = *(const ushort4*)(Hu + (size_t)wid*DD + lane*4);
  f32x4 acc;
  acc.x = aS*u2f(hv.x); acc.y = aS*u2f(hv.y); acc.z = aS*u2f(hv.z); acc.w = aS*u2f(hv.w);
  for(int e = start; e < end; ++e){
    int s = srcList[e];
    float a = alpha[e*HH + head];
    ushort4 v = *(const ushort4*)(Hu + (size_t)(b*NN + s)*DD + lane*4);
    acc.x += a*u2f(v.x); acc.y += a*u2f(v.y); acc.z += a*u2f(v.z); acc.w += a*u2f(v.w);
  }
  float4 bs = *(const float4*)(bias + lane*4);
  float o0 = acc.x + bs.x, o1 = acc.y + bs.y, o2 = acc.z + bs.z, o3 = acc.w + bs.w;
  size_t oi = (size_t)wid*DD + lane*4;
  if(LAYER == 1){
    o0 = o0 > 0.f ? o0 : expm1f(o0);
    o1 = o1 > 0.f ? o1 : expm1f(o1);
    o2 = o2 > 0.f ? o2 : expm1f(o2);
    o3 = o3 > 0.f ? o3 : expm1f(o3);
    ushort4 ov = { f2u(o0), f2u(o1), f2u(o2), f2u(o3) };
    *(ushort4*)((unsigned short*)outp + oi) = ov;
  } else {
    if(*flag){
      float4 ov = { o0, o1, o2, o3 };
      *(float4*)((float*)outp + oi) = ov;
    } else {
      ushort4 ov = { f2u(o0), f2u(o1), f2u(o2), f2u(o3) };
      *(ushort4*)((unsigned short*)outp + oi) = ov;
    }
  }
}

extern "C" void kernel_launch(void* const* d_in, const int* in_sizes, int n_in,
                              void* d_out, int out_size, void* d_ws, size_t ws_size,
                              hipStream_t stream)
{
  const void* x_in = d_in[0];
  const int*  srcI = (const int*)d_in[1];
  const int*  dstI = (const int*)d_in[2];
  const void* W1   = d_in[3];
  const void* as1  = d_in[4];
  const void* ad1  = d_in[5];
  const void* b1   = d_in[6];
  const void* W2   = d_in[7];
  const void* as2  = d_in[8];
  const void* ad2  = d_in[9];
  const void* b2   = d_in[10];

  // Workspace (~70 MiB)
  char* ws = (char*)d_ws;
  __hip_bfloat16* R1  = (__hip_bfloat16*)ws; ws += (size_t)MM*DD*2;        // 32 MiB
  __hip_bfloat16* R2  = (__hip_bfloat16*)ws; ws += (size_t)MM*DD*2;        // 32 MiB
  float* a_src = (float*)ws; ws += (size_t)MM*HH*4;                        // 1 MiB
  float* a_dst = (float*)ws; ws += (size_t)MM*HH*4;                        // 1 MiB
  float* alpha = (float*)ws; ws += (size_t)BB*EE*HH*4;                     // 2 MiB
  float* alphaS= (float*)ws; ws += (size_t)MM*HH*4;                        // 1 MiB
  __hip_bfloat16* W1t = (__hip_bfloat16*)ws; ws += (size_t)DD*DD*2;        // 128 KiB
  __hip_bfloat16* W2t = (__hip_bfloat16*)ws; ws += (size_t)DD*DD*2;        // 128 KiB
  float* attf = (float*)ws; ws += 1536*4;
  int*   degc = (int*)ws;   ws += (size_t)BB*NN*4;
  int*   rowp = (int*)ws;   ws += (size_t)BB*(NN+1)*4;
  unsigned short* srcL = (unsigned short*)ws; ws += (size_t)BB*EE*2;
  int*   flag = (int*)ws;   ws += 8;

  dim3 ggrid(MM/128, DD/128);                      // 512 x 2
  const int attBlocks    = (MM*HH)/256;            // 1024
  const int edgeBlocks   = (BB*EE)/256;            // 512
  const int gatherBlocks = (MM*64)/256;            // 16384

  // ---- dtype detection + canonical params ----
  hipMemsetAsync(degc, 0, (size_t)BB*NN*4, stream);
  detect_kernel<<<1, 64, 0, stream>>>((const unsigned*)x_in, flag);
  convWT_kernel<<<DD*DD/256, 256, 0, stream>>>(W1, W1t, flag);
  convWT_kernel<<<DD*DD/256, 256, 0, stream>>>(W2, W2t, flag);
  conv6_kernel<<<6, 256, 0, stream>>>(as1, ad1, b1, as2, ad2, b2, attf, flag);
  convX_kernel<<<(int)(((size_t)MM*DD)/1024), 256, 0, stream>>>(x_in, (unsigned short*)R1, flag);

  // ---- CSR build ----
  deg_kernel    <<<edgeBlocks, 256, 0, stream>>>(dstI, degc);
  scan_kernel   <<<BB,         256, 0, stream>>>(degc, rowp);
  scatter_kernel<<<edgeBlocks, 256, 0, stream>>>(srcI, dstI, degc, srcL);

  // ---- layer 1 ----
  mfma_gemm<<<ggrid, 256, 0, stream>>>(R1, W1t, R2);
  att_kernel<<<attBlocks, 256, 0, stream>>>(R2, attf + 0, attf + 256, a_src, a_dst);
  alpha_kernel<<<attBlocks, 256, 0, stream>>>(a_src, a_dst, rowp, srcL, alpha, alphaS);
  gather_kernel<1><<<gatherBlocks, 256, 0, stream>>>(R2, alpha, alphaS, rowp, srcL,
                                                     attf + 512, R1, flag);  // R1 = x2
  // ---- layer 2 ----
  mfma_gemm<<<ggrid, 256, 0, stream>>>(R1, W2t, R2);
  att_kernel<<<attBlocks, 256, 0, stream>>>(R2, attf + 768, attf + 1024, a_src, a_dst);
  alpha_kernel<<<attBlocks, 256, 0, stream>>>(a_src, a_dst, rowp, srcL, alpha, alphaS);
  gather_kernel<2><<<gatherBlocks, 256, 0, stream>>>(R2, alpha, alphaS, rowp, srcL,
                                                     attf + 1280, d_out, flag);
}

// Round 6
// 281.482 us; speedup vs baseline: 3.1499x; 1.0953x over previous
//
#include <hip/hip_runtime.h>
#include <hip/hip_bf16.h>
#include <cstdint>

#define BB 32
#define NN 2048
#define EE 4096
#define HH 4
#define CC 64
#define DD 256            // H*C == D_IN
#define MM (BB*NN)        // 65536 rows

typedef __attribute__((ext_vector_type(8))) short bf16x8;
typedef __attribute__((ext_vector_type(4))) float f32x4;

__device__ __forceinline__ float b2f(__hip_bfloat16 x){ return __bfloat162float(x); }
__device__ __forceinline__ float u2f(unsigned short u){ return __uint_as_float((unsigned)u << 16); }
__device__ __forceinline__ unsigned short f2u(float f){
  __hip_bfloat16 h = __float2bfloat16(f);
  return *(unsigned short*)&h;
}
__device__ __forceinline__ float ldany(const void* p, int isf, size_t i){
  return isf ? ((const float*)p)[i] : b2f(((const __hip_bfloat16*)p)[i]);
}
__device__ __forceinline__ void gld_lds16(const void* g, void* l){
  __builtin_amdgcn_global_load_lds((const __attribute__((address_space(1))) uint32_t*)g,
                                   (__attribute__((address_space(3))) uint32_t*)l, 16, 0, 0);
}

// ---------------- dtype detection (unchanged — works) ----------------
__global__ void detect_kernel(const unsigned* __restrict__ w, int* __restrict__ flag){
  __shared__ int cnt;
  if(threadIdx.x == 0) cnt = 0;
  __syncthreads();
  int c = 0;
  #pragma unroll
  for(int i = 0; i < 4; ++i){
    unsigned v = w[threadIdx.x*4 + i];
    unsigned elo = (v >> 7) & 0xFFu;
    if(elo >= 100u && elo <= 150u) ++c;
  }
  atomicAdd(&cnt, c);
  __syncthreads();
  if(threadIdx.x == 0) *flag = (cnt < 128) ? 1 : 0;
}

// ---------------- param prep ----------------
__global__ __launch_bounds__(256) void convX_kernel(const void* __restrict__ src,
    unsigned short* __restrict__ dst, const int* __restrict__ flag){
  int isf = *flag;
  size_t i = ((size_t)blockIdx.x*256 + threadIdx.x)*4;
  ushort4 o;
  if(isf){
    float4 v = *(const float4*)((const float*)src + i);
    o.x = f2u(v.x); o.y = f2u(v.y); o.z = f2u(v.z); o.w = f2u(v.w);
  } else {
    o = *(const ushort4*)((const unsigned short*)src + i);
  }
  *(ushort4*)(dst + i) = o;
}
__global__ __launch_bounds__(256) void convWT_kernel(const void* __restrict__ W,
    __hip_bfloat16* __restrict__ WT, const int* __restrict__ flag){
  int isf = *flag;
  int i = blockIdx.x*256 + threadIdx.x;       // 65536
  WT[i] = __float2bfloat16(ldany(W, isf, (size_t)(i & 255)*256 + (i >> 8)));
}
__global__ __launch_bounds__(256) void conv6_kernel(const void* s0, const void* s1,
    const void* s2, const void* s3, const void* s4, const void* s5,
    float* __restrict__ dst, const int* __restrict__ flag){
  int isf = *flag;
  int i = blockIdx.x*256 + threadIdx.x;       // [0, 1536)
  int seg = i >> 8, off = i & 255;
  const void* s = seg==0?s0 : seg==1?s1 : seg==2?s2 : seg==3?s3 : seg==4?s4 : s5;
  dst[i] = ldany(s, isf, off);
}

// ---------------- MFMA GEMM + fused attention-logit epilogue ----------------
// C[M,256](bf16) = A[M,256](bf16) @ BT[n][k](bf16); also writes
// a_src[row,head] / a_dst[row,head] from the f32 accumulators.
// Each wave's 64 cols == exactly one head's 64 channels.
__global__ __launch_bounds__(256) void mfma_gemm(const __hip_bfloat16* __restrict__ A,
    const __hip_bfloat16* __restrict__ BT, __hip_bfloat16* __restrict__ C,
    const float* __restrict__ attS, const float* __restrict__ attD,
    float* __restrict__ aS, float* __restrict__ aD)
{
  __shared__ __align__(16) short lA[128*64];
  __shared__ __align__(16) short lB[128*64];
  const int tid  = threadIdx.x;
  const int w    = tid >> 6, lane = tid & 63;
  const int row0 = blockIdx.x*128, col0 = blockIdx.y*128;
  const int wr   = (w & 1)*64, wc = (w >> 1)*64;
  const int lr   = lane >> 3;
  const int kb_g = (lane & 7) ^ lr;
  const int fm   = lane & 15, quad = lane >> 4;
  f32x4 acc[4][4] = {};

  for(int k0 = 0; k0 < 256; k0 += 64){
    #pragma unroll
    for(int c = 0; c < 4; ++c){
      int ra = w*32 + c*8;
      const short* ga = (const short*)A  + (size_t)(row0 + ra + lr)*DD + k0 + kb_g*8;
      const short* gb = (const short*)BT + (size_t)(col0 + ra + lr)*DD + k0 + kb_g*8;
      gld_lds16(ga, &lA[ra*64]);
      gld_lds16(gb, &lB[ra*64]);
    }
    __syncthreads();
    #pragma unroll
    for(int ks = 0; ks < 2; ++ks){
      bf16x8 af[4], bfr[4];
      int kb = ks*4 + quad;
      #pragma unroll
      for(int i = 0; i < 4; ++i){
        int m = wr + i*16 + fm;
        af[i]  = *(const bf16x8*)&lA[m*64 + ((kb ^ (m & 7))*8)];
        int n = wc + i*16 + fm;
        bfr[i] = *(const bf16x8*)&lB[n*64 + ((kb ^ (n & 7))*8)];
      }
      #pragma unroll
      for(int i = 0; i < 4; ++i)
        #pragma unroll
        for(int j = 0; j < 4; ++j)
          acc[i][j] = __builtin_amdgcn_mfma_f32_16x16x32_bf16(af[i], bfr[j], acc[i][j], 0, 0, 0);
    }
    __syncthreads();
  }

  // ---- C store (C/D layout: col = lane&15, row = quad*4 + reg) ----
  #pragma unroll
  for(int i = 0; i < 4; ++i)
    #pragma unroll
    for(int j = 0; j < 4; ++j)
      #pragma unroll
      for(int r = 0; r < 4; ++r){
        int row = row0 + wr + i*16 + quad*4 + r;
        int col = col0 + wc + j*16 + fm;
        C[(size_t)row*DD + col] = __float2bfloat16(acc[i][j][r]);
      }

  // ---- fused attention logits ----
  const int headI = (col0 + wc) >> 6;          // this wave's head
  float ws_[4], wd_[4];
  #pragma unroll
  for(int j = 0; j < 4; ++j){
    ws_[j] = attS[headI*CC + j*16 + fm];
    wd_[j] = attD[headI*CC + j*16 + fm];
  }
  #pragma unroll
  for(int i = 0; i < 4; ++i){
    #pragma unroll
    for(int r = 0; r < 4; ++r){
      float s = 0.f, dv = 0.f;
      #pragma unroll
      for(int j = 0; j < 4; ++j){
        float v = acc[i][j][r];
        s  += v * ws_[j];
        dv += v * wd_[j];
      }
      // butterfly over the 16 fm-lanes (bits 0..3; quad bits untouched)
      #pragma unroll
      for(int m = 1; m <= 8; m <<= 1){
        s  += __shfl_xor(s,  m);
        dv += __shfl_xor(dv, m);
      }
      if(fm == i*4 + r){
        int row = row0 + wr + i*16 + quad*4 + r;
        aS[(size_t)row*HH + headI] = s;
        aD[(size_t)row*HH + headI] = dv;
      }
    }
  }
}

// ---------------- CSR build ----------------
__global__ __launch_bounds__(256) void deg_kernel(const int* __restrict__ dst, int* __restrict__ degc)
{
  int idx = blockIdx.x*256 + threadIdx.x;
  if(idx >= BB*EE) return;
  int b = idx >> 12;
  atomicAdd(&degc[b*NN + dst[idx]], 1);
}

__global__ __launch_bounds__(256) void scan_kernel(int* __restrict__ degc, int* __restrict__ row_ptr)
{
  __shared__ int part[256];
  int b = blockIdx.x, t = threadIdx.x;
  int loc[8], s = 0;
  #pragma unroll
  for(int i = 0; i < 8; ++i){ loc[i] = s; s += degc[b*NN + t*8 + i]; }
  part[t] = s;
  __syncthreads();
  if(t == 0){
    int run = 0;
    for(int i = 0; i < 256; ++i){ int tmp = part[i]; part[i] = run; run += tmp; }
  }
  __syncthreads();
  int base = b*EE + part[t];
  #pragma unroll
  for(int i = 0; i < 8; ++i){
    int v = base + loc[i];
    row_ptr[b*(NN+1) + t*8 + i] = v;
    degc   [b*NN     + t*8 + i] = v;
  }
  if(t == 255) row_ptr[b*(NN+1) + NN] = base + s;
}

__global__ __launch_bounds__(256) void scatter_kernel(const int* __restrict__ src,
    const int* __restrict__ dst, int* __restrict__ cursor, unsigned short* __restrict__ srcList)
{
  int idx = blockIdx.x*256 + threadIdx.x;
  if(idx >= BB*EE) return;
  int b = idx >> 12;
  int pos = atomicAdd(&cursor[b*NN + dst[idx]], 1);
  srcList[pos] = (unsigned short)src[idx];
}

// ---------------- raw softmax weights + denominator: one THREAD per (b, dst, head) ----------------
__global__ __launch_bounds__(256) void alpha_kernel(const float* __restrict__ a_src,
    const float* __restrict__ a_dst, const int* __restrict__ row_ptr,
    const unsigned short* __restrict__ srcList, float* __restrict__ alpha,
    float* __restrict__ alphaSelf, float* __restrict__ denG)
{
  int idx = blockIdx.x*256 + threadIdx.x;   // (b*NN + d)*HH + h
  if(idx >= MM*HH) return;
  int h  = idx & (HH-1);
  int bn = idx >> 2;
  int b  = bn >> 11;
  int d  = bn & (NN-1);
  int start = row_ptr[b*(NN+1) + d];
  int end   = row_ptr[b*(NN+1) + d + 1];
  float adv  = a_dst[idx];
  float self = a_src[idx] + adv;
  self = self > 0.f ? self : 0.2f*self;
  float exs = __expf(self), den = exs;
  for(int e = start; e < end; ++e){
    int s = srcList[e];
    float v = a_src[(b*NN + s)*HH + h] + adv;
    v = v > 0.f ? v : 0.2f*v;
    float ex = __expf(v);
    alpha[e*HH + h] = ex;
    den += ex;
  }
  alphaSelf[idx] = exs;
  denG[idx] = den;
}

// ---------------- aggregate: one wave per (b, dst); lane owns 4 channels ----------------
template<int LAYER>
__global__ __launch_bounds__(256) void gather_kernel(const __hip_bfloat16* __restrict__ H,
    const float* __restrict__ alpha, const float* __restrict__ alphaSelf,
    const float* __restrict__ denG,
    const int* __restrict__ row_ptr, const unsigned short* __restrict__ srcList,
    const float* __restrict__ bias, void* __restrict__ outp,
    const int* __restrict__ flag)
{
  int wid  = (int)(((size_t)blockIdx.x*256 + threadIdx.x) >> 6);  // b*NN + d
  int lane = threadIdx.x & 63;
  if(wid >= MM) return;
  int b = wid >> 11, d = wid & (NN-1);
  int head = lane >> 4;
  int start = row_ptr[b*(NN+1) + d];
  int end   = row_ptr[b*(NN+1) + d + 1];
  const unsigned short* Hu = (const unsigned short*)H;

  float aS   = alphaSelf[wid*HH + head];
  float denv = denG[wid*HH + head];
  ushort4 hv = *(const ushort4*)(Hu + (size_t)wid*DD + lane*4);
  f32x4 acc;
  acc.x = aS*u2f(hv.x); acc.y = aS*u2f(hv.y); acc.z = aS*u2f(hv.z); acc.w = aS*u2f(hv.w);

  // software-pipelined edge loop: prefetch next (s, alpha) before using current H row
  int e = start;
  int s  = 0; float a = 0.f;
  if(e < end){ s = srcList[e]; a = alpha[e*HH + head]; }
  while(e < end){
    int   sn = 0; float an = 0.f;
    if(e + 1 < end){ sn = srcList[e+1]; an = alpha[(e+1)*HH + head]; }
    ushort4 v = *(const ushort4*)(Hu + (size_t)(b*NN + s)*DD + lane*4);
    acc.x += a*u2f(v.x); acc.y += a*u2f(v.y); acc.z += a*u2f(v.z); acc.w += a*u2f(v.w);
    s = sn; a = an; ++e;
  }
  float inv = 1.f / (denv + 1e-16f);
  float4 bs = *(const float4*)(bias + lane*4);
  float o0 = acc.x*inv + bs.x, o1 = acc.y*inv + bs.y;
  float o2 = acc.z*inv + bs.z, o3 = acc.w*inv + bs.w;
  size_t oi = (size_t)wid*DD + lane*4;
  if(LAYER == 1){
    o0 = o0 > 0.f ? o0 : expm1f(o0);
    o1 = o1 > 0.f ? o1 : expm1f(o1);
    o2 = o2 > 0.f ? o2 : expm1f(o2);
    o3 = o3 > 0.f ? o3 : expm1f(o3);
    ushort4 ov = { f2u(o0), f2u(o1), f2u(o2), f2u(o3) };
    *(ushort4*)((unsigned short*)outp + oi) = ov;
  } else {
    if(*flag){
      float4 ov = { o0, o1, o2, o3 };
      *(float4*)((float*)outp + oi) = ov;
    } else {
      ushort4 ov = { f2u(o0), f2u(o1), f2u(o2), f2u(o3) };
      *(ushort4*)((unsigned short*)outp + oi) = ov;
    }
  }
}

extern "C" void kernel_launch(void* const* d_in, const int* in_sizes, int n_in,
                              void* d_out, int out_size, void* d_ws, size_t ws_size,
                              hipStream_t stream)
{
  const void* x_in = d_in[0];
  const int*  srcI = (const int*)d_in[1];
  const int*  dstI = (const int*)d_in[2];
  const void* W1   = d_in[3];
  const void* as1  = d_in[4];
  const void* ad1  = d_in[5];
  const void* b1   = d_in[6];
  const void* W2   = d_in[7];
  const void* as2  = d_in[8];
  const void* ad2  = d_in[9];
  const void* b2   = d_in[10];

  // Workspace (~71 MiB)
  char* ws = (char*)d_ws;
  __hip_bfloat16* R1  = (__hip_bfloat16*)ws; ws += (size_t)MM*DD*2;        // 32 MiB
  __hip_bfloat16* R2  = (__hip_bfloat16*)ws; ws += (size_t)MM*DD*2;        // 32 MiB
  float* a_src = (float*)ws; ws += (size_t)MM*HH*4;                        // 1 MiB
  float* a_dst = (float*)ws; ws += (size_t)MM*HH*4;                        // 1 MiB
  float* alpha = (float*)ws; ws += (size_t)BB*EE*HH*4;                     // 2 MiB
  float* alphaS= (float*)ws; ws += (size_t)MM*HH*4;                        // 1 MiB
  float* denG  = (float*)ws; ws += (size_t)MM*HH*4;                        // 1 MiB
  __hip_bfloat16* W1t = (__hip_bfloat16*)ws; ws += (size_t)DD*DD*2;        // 128 KiB
  __hip_bfloat16* W2t = (__hip_bfloat16*)ws; ws += (size_t)DD*DD*2;        // 128 KiB
  float* attf = (float*)ws; ws += 1536*4;
  int*   degc = (int*)ws;   ws += (size_t)BB*NN*4;
  int*   rowp = (int*)ws;   ws += (size_t)BB*(NN+1)*4;
  unsigned short* srcL = (unsigned short*)ws; ws += (size_t)BB*EE*2;
  int*   flag = (int*)ws;   ws += 8;

  dim3 ggrid(MM/128, DD/128);                      // 512 x 2
  const int attBlocks    = (MM*HH)/256;            // 1024
  const int edgeBlocks   = (BB*EE)/256;            // 512
  const int gatherBlocks = (MM*64)/256;            // 16384

  // ---- dtype detection + canonical params ----
  hipMemsetAsync(degc, 0, (size_t)BB*NN*4, stream);
  detect_kernel<<<1, 64, 0, stream>>>((const unsigned*)x_in, flag);
  convWT_kernel<<<DD*DD/256, 256, 0, stream>>>(W1, W1t, flag);
  convWT_kernel<<<DD*DD/256, 256, 0, stream>>>(W2, W2t, flag);
  conv6_kernel<<<6, 256, 0, stream>>>(as1, ad1, b1, as2, ad2, b2, attf, flag);
  convX_kernel<<<(int)(((size_t)MM*DD)/1024), 256, 0, stream>>>(x_in, (unsigned short*)R1, flag);

  // ---- CSR build ----
  deg_kernel    <<<edgeBlocks, 256, 0, stream>>>(dstI, degc);
  scan_kernel   <<<BB,         256, 0, stream>>>(degc, rowp);
  scatter_kernel<<<edgeBlocks, 256, 0, stream>>>(srcI, dstI, degc, srcL);

  // ---- layer 1 ----
  mfma_gemm<<<ggrid, 256, 0, stream>>>(R1, W1t, R2, attf + 0, attf + 256, a_src, a_dst);
  alpha_kernel<<<attBlocks, 256, 0, stream>>>(a_src, a_dst, rowp, srcL, alpha, alphaS, denG);
  gather_kernel<1><<<gatherBlocks, 256, 0, stream>>>(R2, alpha, alphaS, denG, rowp, srcL,
                                                     attf + 512, R1, flag);  // R1 = x2
  // ---- layer 2 ----
  mfma_gemm<<<ggrid, 256, 0, stream>>>(R1, W2t, R2, attf + 768, attf + 1024, a_src, a_dst);
  alpha_kernel<<<attBlocks, 256, 0, stream>>>(a_src, a_dst, rowp, srcL, alpha, alphaS, denG);
  gather_kernel<2><<<gatherBlocks, 256, 0, stream>>>(R2, alpha, alphaS, denG, rowp, srcL,
                                                     attf + 1280, d_out, flag);
}